// Round 4
// baseline (716.455 us; speedup 1.0000x reference)
//
#include <hip/hip_runtime.h>
#include <hip/hip_bf16.h>
#include <stdint.h>

// Problem constants
#define T_TOK 8192   // B*S tokens
#define HID   2048
#define OUTD  2048
#define NE    8
#define RR    16
#define KAUG  2176   // 2048 + NE*RR
#define NH    128    // h columns (NE*RR)

typedef __bf16 bf16x8 __attribute__((ext_vector_type(8)));
typedef float  f32x4  __attribute__((ext_vector_type(4)));
typedef unsigned short u16x8 __attribute__((ext_vector_type(8)));

#define AS1(p) ((__attribute__((address_space(1))) void*)(p))
#define AS3(p) ((__attribute__((address_space(3))) void*)(p))

__device__ inline unsigned short f2bf(float f) {
  unsigned int u = __builtin_bit_cast(unsigned int, f);
  unsigned int r = (u + 0x7fffu + ((u >> 16) & 1u)) >> 16;   // RNE
  return (unsigned short)r;
}

__device__ inline ushort4 f2bf4(float4 v) {
  ushort4 u;
  u.x = f2bf(v.x); u.y = f2bf(v.y); u.z = f2bf(v.z); u.w = f2bf(v.w);
  return u;
}

// 8 f32 -> 8 bf16, one 16B LDS store (ds_write_b128; dest is 16B-aligned)
__device__ inline void st8(unsigned short* p, float4 a, float4 b) {
  u16x8 v;
  v[0] = f2bf(a.x); v[1] = f2bf(a.y); v[2] = f2bf(a.z); v[3] = f2bf(a.w);
  v[4] = f2bf(b.x); v[5] = f2bf(b.y); v[6] = f2bf(b.z); v[7] = f2bf(b.w);
  *(u16x8*)p = v;
}

// ---- fused K1: router + Xa-core + h-aug cols + W/B converts ----
// blocks [0,256):    32 tokens each.
//   phase 1 (verbatim router math, bit-identical per-lane accumulation):
//     gw staged in LDS f32; wave w handles tokens w*4..w*4+3 sequentially;
//     writes Xa core bf16 + wte -> LDS (no global round-trip).
//   phase 2 (h-GEMM 32x128, K=2048): ring-of-3 LDS, counted vmcnt.
//     Xs: global_load_lds of this block's OWN just-written Xa rows (L2-hot),
//     pre-swizzled source, waves 0-3.  As: reg-staged from f32 A (1 MB,
//     L3-resident) -> f2bf -> swizzled ds_write_b128; compiler tracks the
//     A-register loads with its own waitcnts, so the hand vmcnt(5) counts
//     only the fixed 4 A-loads + 1 gll issued per region ("memory"-clobbered
//     asm pins region boundaries).  Epilogue scales by wte_s and writes aug cols.
// blocks [256,2304):  W convert (verbatim round-3)
// blocks [2304,2432): B convert (verbatim round-3, correct 128 blocks)
__global__ __launch_bounds__(512, 4) void k_fused(const float* __restrict__ x,
                                                  const float* __restrict__ gw,
                                                  const float* __restrict__ A,
                                                  const float* __restrict__ W,
                                                  const float* __restrict__ Bw,
                                                  unsigned short* __restrict__ Xa,
                                                  unsigned short* __restrict__ Wa) {
  __shared__ union {
    float gws[NE * HID];                       // 64 KiB (phase 1)
    struct {
      unsigned short Xs[3][32 * 64];           // 12 KiB
      unsigned short As[3][128 * 64];          // 48 KiB
    } r;                                       // 60 KiB (phase 2)
  } sh;
  __shared__ float wte_s[32][8];               // 1 KiB

  if (blockIdx.x >= 256) {
    int b2 = blockIdx.x - 256;
    if (b2 < 2048) {                       // W: 2048 blocks * 512 thr * float4
      int tid = b2 * 512 + threadIdx.x;
      int row = tid >> 9, c = (tid & 511) << 2;
      float4 v = *(const float4*)(W + (size_t)row * HID + c);
      *(ushort4*)(Wa + (size_t)row * KAUG + c) = f2bf4(v);
    } else {                               // B: 128 blocks * 512 thr * float4
      int tid = (b2 - 2048) * 512 + threadIdx.x;
      int o = tid >> 5, j = (tid & 31) << 2;
      int e = j >> 4, r = j & 15;
      float4 v = *(const float4*)(Bw + (size_t)e * OUTD * RR + (size_t)o * RR + r);
      *(ushort4*)(Wa + (size_t)o * KAUG + 2048 + j) = f2bf4(v);
    }
    return;
  }

  int w = threadIdx.x >> 6, lane = threadIdx.x & 63;
  int tm = blockIdx.x * 32;

  // ================= phase 1: router + Xa core =================
#pragma unroll
  for (int i = 0; i < 8; ++i) {
    int idx = (i * 512 + (int)threadIdx.x) * 4;
    *(float4*)(sh.gws + idx) = *(const float4*)(gw + idx);
  }
  __syncthreads();
#pragma unroll 1
  for (int j = 0; j < 4; ++j) {
    int t = tm + w * 4 + j;
    const float* xt = x + (size_t)t * HID;
    unsigned short* xo = Xa + (size_t)t * KAUG;
    double acc[8] = {0, 0, 0, 0, 0, 0, 0, 0};
#pragma unroll
    for (int i = 0; i < 8; ++i) {
      int k = (i * 64 + lane) * 4;
      float4 xv = *(const float4*)(xt + k);
      *(ushort4*)(xo + k) = f2bf4(xv);
#pragma unroll
      for (int e = 0; e < 8; ++e) {
        float4 gv = *(const float4*)(sh.gws + e * HID + k);
        acc[e] += (double)xv.x * gv.x + (double)xv.y * gv.y +
                  (double)xv.z * gv.z + (double)xv.w * gv.w;
      }
    }
#pragma unroll
    for (int off = 32; off >= 1; off >>= 1)
#pragma unroll
      for (int e = 0; e < 8; ++e)
        acc[e] += __shfl_down(acc[e], off, 64);
    if (lane == 0) {
      int e0 = 0; double l0 = acc[0];
#pragma unroll
      for (int e = 1; e < 8; ++e) if (acc[e] > l0) { l0 = acc[e]; e0 = e; }
      int e1 = -1; double l1 = -1e300;
#pragma unroll
      for (int e = 0; e < 8; ++e) if (e != e0 && acc[e] > l1) { l1 = acc[e]; e1 = e; }
      double w0 = 16.0 / (1.0 + exp(l1 - l0));
      float o[8] = {0.f, 0.f, 0.f, 0.f, 0.f, 0.f, 0.f, 0.f};
      o[e0] = (float)w0;
      o[e1] = (float)(16.0 - w0);
      float4* p = (float4*)(&wte_s[w * 4 + j][0]);
      p[0] = make_float4(o[0], o[1], o[2], o[3]);
      p[1] = make_float4(o[4], o[5], o[6], o[7]);
    }
  }
  __threadfence();      // Xa-core stores visible before phase-2 re-reads
  __syncthreads();      // (implicit vmcnt(0) drain) + wte_s/gws->ring handoff

  // ================= phase 2: h-GEMM =================
  int wlt4 = (w < 4);
  int wm = (w >> 2) * 16, wn = (w & 3) * 32;
  int lrow = lane >> 3;
  int lcol_s = (lane & 7) << 3;                       // LDS dest (contiguous)
  int lcol_g = ((lane & 7) ^ (lrow & 7)) << 3;        // swizzled global source
  const unsigned short* gX = Xa + (size_t)(tm + (w & 3) * 8 + lrow) * KAUG + lcol_g;
  int sxo = ((w & 3) * 8 + lrow) * 64 + lcol_s;

  // A reg-stage mapping: idx = it*512+tid -> (col, kg); 2 slots/thread
  int ia0 = (int)threadIdx.x, ia1 = 512 + (int)threadIdx.x;
  int colA0 = ia0 >> 3, kgA0 = ia0 & 7;
  int colA1 = ia1 >> 3, kgA1 = ia1 & 7;
  const float* gA0 = A + (size_t)colA0 * HID + kgA0 * 8;
  const float* gA1 = A + (size_t)colA1 * HID + kgA1 * 8;
  int sa0 = colA0 * 64 + ((kgA0 ^ (colA0 & 7)) << 3); // swizzled LDS dest (shorts)
  int sa1 = colA1 * 64 + ((kgA1 ^ (colA1 & 7)) << 3);

  f32x4 acc2[2] = {};
  float4 ab0_0, ab0_1, ab0_2, ab0_3;                  // A double-buffer (named: static idx)
  float4 ab1_0, ab1_1, ab1_2, ab1_3;

#define A_ISSUE(B, T) do {                                            \
    ab##B##_0 = *(const float4*)(gA0 + (size_t)(T) * 64);             \
    ab##B##_1 = *(const float4*)(gA0 + (size_t)(T) * 64 + 4);         \
    ab##B##_2 = *(const float4*)(gA1 + (size_t)(T) * 64);             \
    ab##B##_3 = *(const float4*)(gA1 + (size_t)(T) * 64 + 4);         \
  } while (0)

#define CVT_DSW(B, S) do {                                            \
    st8(&sh.r.As[S][sa0], ab##B##_0, ab##B##_1);                      \
    st8(&sh.r.As[S][sa1], ab##B##_2, ab##B##_3);                      \
  } while (0)

#define XS_ISSUE(S, T) do {                                           \
    if (wlt4)                                                         \
      __builtin_amdgcn_global_load_lds(AS1(gX + (size_t)(T) * 64),    \
                                       AS3(&sh.r.Xs[S][0] + sxo), 16, 0, 0); \
  } while (0)

#define HCOMP(S) do {                                                 \
    _Pragma("unroll")                                                 \
    for (int ks = 0; ks < 2; ++ks) {                                  \
      int kch = ks * 4 + (lane >> 4);                                 \
      int ko = ((kch ^ (lane & 7)) << 3);                             \
      bf16x8 av = *(const bf16x8*)(&sh.r.Xs[S][0] + (wm + (lane & 15)) * 64 + ko); \
      _Pragma("unroll")                                               \
      for (int fn = 0; fn < 2; ++fn) {                                \
        bf16x8 bv = *(const bf16x8*)(&sh.r.As[S][0] + (wn + fn * 16 + (lane & 15)) * 64 + ko); \
        acc2[fn] = __builtin_amdgcn_mfma_f32_16x16x32_bf16(av, bv, acc2[fn], 0, 0, 0); \
      }                                                               \
    }                                                                 \
  } while (0)

// one steady iteration: t -> ST=t%3, SCV=(t+1)%3, SIS=(t+2)%3, BCV=(t+1)&1, BIS=t&1.
// vmcnt(5) = loads newer than Xs(t): 4 A-loads(t+1) + 1 gll(t+1). Waves 4-7 issue no
// gll -> lgkm-only wait.  Slot safety: Xs/A writes to slot s only after the barrier
// following s's last read (ring-of-3 discipline, proven round-1/3).
#define PH2_BODY(T, ST, SCV, SIS, BCV, BIS) do {                      \
    if (wlt4) asm volatile("s_waitcnt vmcnt(5) lgkmcnt(0)" ::: "memory"); \
    else      asm volatile("s_waitcnt lgkmcnt(0)" ::: "memory");      \
    __builtin_amdgcn_s_barrier();                                     \
    CVT_DSW(BCV, SCV);                                                \
    A_ISSUE(BIS, (T) + 2);                                            \
    XS_ISSUE(SIS, (T) + 2);                                           \
    HCOMP(ST);                                                        \
  } while (0)

  // prologue: tiles 0,1 in flight; convert A0 into slot 0
  A_ISSUE(0, 0);
  XS_ISSUE(0, 0);
  A_ISSUE(1, 1);
  XS_ISSUE(1, 1);
  CVT_DSW(0, 0);

  // t = 0..29 (6-unrolled so all slot/buffer indices are compile-time)
  for (int tt = 0; tt < 30; tt += 6) {
    PH2_BODY(tt + 0, 0, 1, 2, 1, 0);
    PH2_BODY(tt + 1, 1, 2, 0, 0, 1);
    PH2_BODY(tt + 2, 2, 0, 1, 1, 0);
    PH2_BODY(tt + 3, 0, 1, 2, 0, 1);
    PH2_BODY(tt + 4, 1, 2, 0, 1, 0);
    PH2_BODY(tt + 5, 2, 0, 1, 0, 1);
  }
  // t = 30: cvt A31 (buf 1) -> slot 1; compute slot 0
  if (wlt4) asm volatile("s_waitcnt vmcnt(5) lgkmcnt(0)" ::: "memory");
  else      asm volatile("s_waitcnt lgkmcnt(0)" ::: "memory");
  __builtin_amdgcn_s_barrier();
  CVT_DSW(1, 1);
  HCOMP(0);
  // t = 31: compute slot 1
  asm volatile("s_waitcnt vmcnt(0) lgkmcnt(0)" ::: "memory");
  __builtin_amdgcn_s_barrier();
  HCOMP(1);

#undef A_ISSUE
#undef CVT_DSW
#undef XS_ISSUE
#undef HCOMP
#undef PH2_BODY

  // epilogue: scale by router weight, write bf16 aug cols
  int q = lane >> 4;
#pragma unroll
  for (int fn = 0; fn < 2; ++fn) {
    int col = wn + fn * 16 + (lane & 15);              // 0..127
    int e = col >> 4;
#pragma unroll
    for (int r = 0; r < 4; ++r) {
      int tl = wm + q * 4 + r;                         // 0..31
      float we = wte_s[tl][e];
      Xa[(size_t)(tm + tl) * KAUG + 2048 + col] = f2bf(we * acc2[fn][r]);
    }
  }
}

// ---- main GEMM: out[t][o] = sum_{k<2176} Xa[t][k]*Wa[o][k] ----
// m97 structure + XOR-swizzled LDS + XCD swizzle. UNCHANGED (proven 76 us / 960 TF).
__global__ __launch_bounds__(256, 4) void k_gemm(const unsigned short* __restrict__ Xa,
                                                 const unsigned short* __restrict__ Wa,
                                                 float* __restrict__ out) {
  __shared__ unsigned short As[128 * 64];
  __shared__ unsigned short Bs[128 * 64];
  int lid = blockIdx.x;                 // grid = 1024 linear
  int xcd = lid & 7, s = lid >> 3;
  int bm = (xcd * 8 + (s & 7)) * 128;   // 0..63
  int bn = (s >> 3) * 128;              // 0..15
  int w = threadIdx.x >> 6, lane = threadIdx.x & 63;
  int wm = (w >> 1) * 64, wn = (w & 1) * 64;
  int lrow = lane >> 3;
  int lcol_s = (lane & 7) << 3;
  int lcol_g = ((lane & 7) ^ (lrow & 7)) << 3;

  const unsigned short* gA = Xa + (size_t)(bm + w * 32 + lrow) * KAUG + lcol_g;
  const unsigned short* gB = Wa + (size_t)(bn + w * 32 + lrow) * KAUG + lcol_g;
  unsigned short* sA = As + (w * 32 + lrow) * 64 + lcol_s;
  unsigned short* sB = Bs + (w * 32 + lrow) * 64 + lcol_s;

  f32x4 acc[4][4] = {};
  for (int kt = 0; kt < KAUG; kt += 64) {
#pragma unroll
    for (int i = 0; i < 4; ++i) {
      __builtin_amdgcn_global_load_lds(AS1(gA + (size_t)i * 8 * KAUG), AS3(sA + i * 8 * 64), 16, 0, 0);
      __builtin_amdgcn_global_load_lds(AS1(gB + (size_t)i * 8 * KAUG), AS3(sB + i * 8 * 64), 16, 0, 0);
    }
    __syncthreads();
#pragma unroll
    for (int ks = 0; ks < 2; ++ks) {
      int kch = ks * 4 + (lane >> 4);
      int ko = ((kch ^ (lane & 7)) << 3);             // swizzled read offset
      bf16x8 a[4], b[4];
#pragma unroll
      for (int f = 0; f < 4; ++f) a[f] = *(const bf16x8*)(As + (wm + f * 16 + (lane & 15)) * 64 + ko);
#pragma unroll
      for (int f = 0; f < 4; ++f) b[f] = *(const bf16x8*)(Bs + (wn + f * 16 + (lane & 15)) * 64 + ko);
#pragma unroll
      for (int fm = 0; fm < 4; ++fm)
#pragma unroll
        for (int fn = 0; fn < 4; ++fn)
          acc[fm][fn] = __builtin_amdgcn_mfma_f32_16x16x32_bf16(a[fm], b[fn], acc[fm][fn], 0, 0, 0);
    }
    __syncthreads();
    gA += 64; gB += 64;
  }
#pragma unroll
  for (int fm = 0; fm < 4; ++fm) {
    int row = bm + wm + fm * 16 + ((lane >> 4) << 2);
#pragma unroll
    for (int r = 0; r < 4; ++r) {
      float* orow = out + (size_t)(row + r) * OUTD + bn + wn + (lane & 15);
#pragma unroll
      for (int fn = 0; fn < 4; ++fn) orow[fn * 16] = acc[fm][fn][r];
    }
  }
}

extern "C" void kernel_launch(void* const* d_in, const int* in_sizes, int n_in,
                              void* d_out, int out_size, void* d_ws, size_t ws_size,
                              hipStream_t stream) {
  const float* x  = (const float*)d_in[0];
  const float* W  = (const float*)d_in[1];
  const float* gw = (const float*)d_in[2];
  const float* A  = (const float*)d_in[3];
  const float* B  = (const float*)d_in[4];
  float* out = (float*)d_out;

  char* ws = (char*)d_ws;
  unsigned short* Xa = (unsigned short*)(ws);                  // 8192*2176*2 = 35,651,584
  unsigned short* Wa = (unsigned short*)(ws + 35651584);       // 2048*2176*2 =  8,912,896
  // total 44,564,480 bytes (Ag / wte eliminated)

  k_fused<<<2432, 512, 0, stream>>>(x, gw, A, W, B, Xa, Wa);
  k_gemm <<<1024, 256, 0, stream>>>(Xa, Wa, out);
}

// Round 5
// 544.145 us; speedup vs baseline: 1.3167x; 1.3167x over previous
//
#include <hip/hip_runtime.h>
#include <hip/hip_bf16.h>
#include <stdint.h>

// Problem constants
#define T_TOK 8192   // B*S tokens
#define HID   2048
#define OUTD  2048
#define NE    8
#define RR    16
#define KAUG  2176   // 2048 + NE*RR
#define NH    128    // h columns (NE*RR)

typedef __bf16 bf16x8 __attribute__((ext_vector_type(8)));
typedef float  f32x4  __attribute__((ext_vector_type(4)));
typedef unsigned short u16x8 __attribute__((ext_vector_type(8)));

#define AS1(p) ((__attribute__((address_space(1))) void*)(p))
#define AS3(p) ((__attribute__((address_space(3))) void*)(p))

__device__ inline unsigned short f2bf(float f) {
  unsigned int u = __builtin_bit_cast(unsigned int, f);
  unsigned int r = (u + 0x7fffu + ((u >> 16) & 1u)) >> 16;   // RNE
  return (unsigned short)r;
}

__device__ inline ushort4 f2bf4(float4 v) {
  ushort4 u;
  u.x = f2bf(v.x); u.y = f2bf(v.y); u.z = f2bf(v.z); u.w = f2bf(v.w);
  return u;
}

// 8 f32 -> 8 bf16, one 16B LDS store (ds_write_b128; dest is 16B-aligned)
__device__ inline void st8(unsigned short* p, float4 a, float4 b) {
  u16x8 v;
  v[0] = f2bf(a.x); v[1] = f2bf(a.y); v[2] = f2bf(a.z); v[3] = f2bf(a.w);
  v[4] = f2bf(b.x); v[5] = f2bf(b.y); v[6] = f2bf(b.z); v[7] = f2bf(b.w);
  *(u16x8*)p = v;
}

// ---- fused K1: router + Xa-core + h-aug cols + W/B converts ----
// IDENTICAL arithmetic to round-4 (passed absmax 0.03125). ONLY change:
// __launch_bounds__(512,4) -> __launch_bounds__(512). The min-waves=4 clause
// capped VGPRs at 64 (counters: VGPR_Count=64) while the kernel's live set is
// ~100+ regs (8 float4 A-buffers + 8 fp64 router accs) -> massive scratch
// spills (FETCH 521MB / WRITE 274MB vs expected 134/46) -> 550us. LDS (65KiB)
// governs residency anyway (2 blocks/CU); the register cap bought nothing.
__global__ __launch_bounds__(512) void k_fused(const float* __restrict__ x,
                                               const float* __restrict__ gw,
                                               const float* __restrict__ A,
                                               const float* __restrict__ W,
                                               const float* __restrict__ Bw,
                                               unsigned short* __restrict__ Xa,
                                               unsigned short* __restrict__ Wa) {
  __shared__ union {
    float gws[NE * HID];                       // 64 KiB (phase 1)
    struct {
      unsigned short Xs[3][32 * 64];           // 12 KiB
      unsigned short As[3][128 * 64];          // 48 KiB
    } r;                                       // 60 KiB (phase 2)
  } sh;
  __shared__ float wte_s[32][8];               // 1 KiB

  if (blockIdx.x >= 256) {
    int b2 = blockIdx.x - 256;
    if (b2 < 2048) {                       // W: 2048 blocks * 512 thr * float4
      int tid = b2 * 512 + threadIdx.x;
      int row = tid >> 9, c = (tid & 511) << 2;
      float4 v = *(const float4*)(W + (size_t)row * HID + c);
      *(ushort4*)(Wa + (size_t)row * KAUG + c) = f2bf4(v);
    } else {                               // B: 128 blocks * 512 thr * float4
      int tid = (b2 - 2048) * 512 + threadIdx.x;
      int o = tid >> 5, j = (tid & 31) << 2;
      int e = j >> 4, r = j & 15;
      float4 v = *(const float4*)(Bw + (size_t)e * OUTD * RR + (size_t)o * RR + r);
      *(ushort4*)(Wa + (size_t)o * KAUG + 2048 + j) = f2bf4(v);
    }
    return;
  }

  int w = threadIdx.x >> 6, lane = threadIdx.x & 63;
  int tm = blockIdx.x * 32;

  // ================= phase 1: router + Xa core =================
#pragma unroll
  for (int i = 0; i < 8; ++i) {
    int idx = (i * 512 + (int)threadIdx.x) * 4;
    *(float4*)(sh.gws + idx) = *(const float4*)(gw + idx);
  }
  __syncthreads();
#pragma unroll 1
  for (int j = 0; j < 4; ++j) {
    int t = tm + w * 4 + j;
    const float* xt = x + (size_t)t * HID;
    unsigned short* xo = Xa + (size_t)t * KAUG;
    double acc[8] = {0, 0, 0, 0, 0, 0, 0, 0};
#pragma unroll
    for (int i = 0; i < 8; ++i) {
      int k = (i * 64 + lane) * 4;
      float4 xv = *(const float4*)(xt + k);
      *(ushort4*)(xo + k) = f2bf4(xv);
#pragma unroll
      for (int e = 0; e < 8; ++e) {
        float4 gv = *(const float4*)(sh.gws + e * HID + k);
        acc[e] += (double)xv.x * gv.x + (double)xv.y * gv.y +
                  (double)xv.z * gv.z + (double)xv.w * gv.w;
      }
    }
#pragma unroll
    for (int off = 32; off >= 1; off >>= 1)
#pragma unroll
      for (int e = 0; e < 8; ++e)
        acc[e] += __shfl_down(acc[e], off, 64);
    if (lane == 0) {
      int e0 = 0; double l0 = acc[0];
#pragma unroll
      for (int e = 1; e < 8; ++e) if (acc[e] > l0) { l0 = acc[e]; e0 = e; }
      int e1 = -1; double l1 = -1e300;
#pragma unroll
      for (int e = 0; e < 8; ++e) if (e != e0 && acc[e] > l1) { l1 = acc[e]; e1 = e; }
      double w0 = 16.0 / (1.0 + exp(l1 - l0));
      float o[8] = {0.f, 0.f, 0.f, 0.f, 0.f, 0.f, 0.f, 0.f};
      o[e0] = (float)w0;
      o[e1] = (float)(16.0 - w0);
      float4* p = (float4*)(&wte_s[w * 4 + j][0]);
      p[0] = make_float4(o[0], o[1], o[2], o[3]);
      p[1] = make_float4(o[4], o[5], o[6], o[7]);
    }
  }
  __threadfence();      // Xa-core stores visible before phase-2 re-reads
  __syncthreads();      // (implicit vmcnt(0) drain) + wte_s/gws->ring handoff

  // ================= phase 2: h-GEMM =================
  int wlt4 = (w < 4);
  int wm = (w >> 2) * 16, wn = (w & 3) * 32;
  int lrow = lane >> 3;
  int lcol_s = (lane & 7) << 3;                       // LDS dest (contiguous)
  int lcol_g = ((lane & 7) ^ (lrow & 7)) << 3;        // swizzled global source
  const unsigned short* gX = Xa + (size_t)(tm + (w & 3) * 8 + lrow) * KAUG + lcol_g;
  int sxo = ((w & 3) * 8 + lrow) * 64 + lcol_s;

  // A reg-stage mapping: idx = it*512+tid -> (col, kg); 2 slots/thread
  int ia0 = (int)threadIdx.x, ia1 = 512 + (int)threadIdx.x;
  int colA0 = ia0 >> 3, kgA0 = ia0 & 7;
  int colA1 = ia1 >> 3, kgA1 = ia1 & 7;
  const float* gA0 = A + (size_t)colA0 * HID + kgA0 * 8;
  const float* gA1 = A + (size_t)colA1 * HID + kgA1 * 8;
  int sa0 = colA0 * 64 + ((kgA0 ^ (colA0 & 7)) << 3); // swizzled LDS dest (shorts)
  int sa1 = colA1 * 64 + ((kgA1 ^ (colA1 & 7)) << 3);

  f32x4 acc2[2] = {};
  float4 ab0_0, ab0_1, ab0_2, ab0_3;                  // A double-buffer (named: static idx)
  float4 ab1_0, ab1_1, ab1_2, ab1_3;

#define A_ISSUE(B, T) do {                                            \
    ab##B##_0 = *(const float4*)(gA0 + (size_t)(T) * 64);             \
    ab##B##_1 = *(const float4*)(gA0 + (size_t)(T) * 64 + 4);         \
    ab##B##_2 = *(const float4*)(gA1 + (size_t)(T) * 64);             \
    ab##B##_3 = *(const float4*)(gA1 + (size_t)(T) * 64 + 4);         \
  } while (0)

#define CVT_DSW(B, S) do {                                            \
    st8(&sh.r.As[S][sa0], ab##B##_0, ab##B##_1);                      \
    st8(&sh.r.As[S][sa1], ab##B##_2, ab##B##_3);                      \
  } while (0)

#define XS_ISSUE(S, T) do {                                           \
    if (wlt4)                                                         \
      __builtin_amdgcn_global_load_lds(AS1(gX + (size_t)(T) * 64),    \
                                       AS3(&sh.r.Xs[S][0] + sxo), 16, 0, 0); \
  } while (0)

#define HCOMP(S) do {                                                 \
    _Pragma("unroll")                                                 \
    for (int ks = 0; ks < 2; ++ks) {                                  \
      int kch = ks * 4 + (lane >> 4);                                 \
      int ko = ((kch ^ (lane & 7)) << 3);                             \
      bf16x8 av = *(const bf16x8*)(&sh.r.Xs[S][0] + (wm + (lane & 15)) * 64 + ko); \
      _Pragma("unroll")                                               \
      for (int fn = 0; fn < 2; ++fn) {                                \
        bf16x8 bv = *(const bf16x8*)(&sh.r.As[S][0] + (wn + fn * 16 + (lane & 15)) * 64 + ko); \
        acc2[fn] = __builtin_amdgcn_mfma_f32_16x16x32_bf16(av, bv, acc2[fn], 0, 0, 0); \
      }                                                               \
    }                                                                 \
  } while (0)

// one steady iteration: t -> ST=t%3, SCV=(t+1)%3, SIS=(t+2)%3, BCV=(t+1)&1, BIS=t&1.
// vmcnt(5) = loads newer than Xs(t): 4 A-loads(t+1) + 1 gll(t+1). Waves 4-7 issue no
// gll -> lgkm-only wait.  Slot safety: Xs/A writes to slot s only after the barrier
// following s's last read (ring-of-3 discipline, proven round-1/3).
#define PH2_BODY(T, ST, SCV, SIS, BCV, BIS) do {                      \
    if (wlt4) asm volatile("s_waitcnt vmcnt(5) lgkmcnt(0)" ::: "memory"); \
    else      asm volatile("s_waitcnt lgkmcnt(0)" ::: "memory");      \
    __builtin_amdgcn_s_barrier();                                     \
    CVT_DSW(BCV, SCV);                                                \
    A_ISSUE(BIS, (T) + 2);                                            \
    XS_ISSUE(SIS, (T) + 2);                                           \
    HCOMP(ST);                                                        \
  } while (0)

  // prologue: tiles 0,1 in flight; convert A0 into slot 0
  A_ISSUE(0, 0);
  XS_ISSUE(0, 0);
  A_ISSUE(1, 1);
  XS_ISSUE(1, 1);
  CVT_DSW(0, 0);

  // t = 0..29 (6-unrolled so all slot/buffer indices are compile-time)
  for (int tt = 0; tt < 30; tt += 6) {
    PH2_BODY(tt + 0, 0, 1, 2, 1, 0);
    PH2_BODY(tt + 1, 1, 2, 0, 0, 1);
    PH2_BODY(tt + 2, 2, 0, 1, 1, 0);
    PH2_BODY(tt + 3, 0, 1, 2, 0, 1);
    PH2_BODY(tt + 4, 1, 2, 0, 1, 0);
    PH2_BODY(tt + 5, 2, 0, 1, 0, 1);
  }
  // t = 30: cvt A31 (buf 1) -> slot 1; compute slot 0
  if (wlt4) asm volatile("s_waitcnt vmcnt(5) lgkmcnt(0)" ::: "memory");
  else      asm volatile("s_waitcnt lgkmcnt(0)" ::: "memory");
  __builtin_amdgcn_s_barrier();
  CVT_DSW(1, 1);
  HCOMP(0);
  // t = 31: compute slot 1
  asm volatile("s_waitcnt vmcnt(0) lgkmcnt(0)" ::: "memory");
  __builtin_amdgcn_s_barrier();
  HCOMP(1);

#undef A_ISSUE
#undef CVT_DSW
#undef XS_ISSUE
#undef HCOMP
#undef PH2_BODY

  // epilogue: scale by router weight, write bf16 aug cols
  int q = lane >> 4;
#pragma unroll
  for (int fn = 0; fn < 2; ++fn) {
    int col = wn + fn * 16 + (lane & 15);              // 0..127
    int e = col >> 4;
#pragma unroll
    for (int r = 0; r < 4; ++r) {
      int tl = wm + q * 4 + r;                         // 0..31
      float we = wte_s[tl][e];
      Xa[(size_t)(tm + tl) * KAUG + 2048 + col] = f2bf(we * acc2[fn][r]);
    }
  }
}

// ---- main GEMM: out[t][o] = sum_{k<2176} Xa[t][k]*Wa[o][k] ----
// m97 structure + XOR-swizzled LDS + XCD swizzle. UNCHANGED (proven 76 us / 960 TF).
__global__ __launch_bounds__(256, 4) void k_gemm(const unsigned short* __restrict__ Xa,
                                                 const unsigned short* __restrict__ Wa,
                                                 float* __restrict__ out) {
  __shared__ unsigned short As[128 * 64];
  __shared__ unsigned short Bs[128 * 64];
  int lid = blockIdx.x;                 // grid = 1024 linear
  int xcd = lid & 7, s = lid >> 3;
  int bm = (xcd * 8 + (s & 7)) * 128;   // 0..63
  int bn = (s >> 3) * 128;              // 0..15
  int w = threadIdx.x >> 6, lane = threadIdx.x & 63;
  int wm = (w >> 1) * 64, wn = (w & 1) * 64;
  int lrow = lane >> 3;
  int lcol_s = (lane & 7) << 3;
  int lcol_g = ((lane & 7) ^ (lrow & 7)) << 3;

  const unsigned short* gA = Xa + (size_t)(bm + w * 32 + lrow) * KAUG + lcol_g;
  const unsigned short* gB = Wa + (size_t)(bn + w * 32 + lrow) * KAUG + lcol_g;
  unsigned short* sA = As + (w * 32 + lrow) * 64 + lcol_s;
  unsigned short* sB = Bs + (w * 32 + lrow) * 64 + lcol_s;

  f32x4 acc[4][4] = {};
  for (int kt = 0; kt < KAUG; kt += 64) {
#pragma unroll
    for (int i = 0; i < 4; ++i) {
      __builtin_amdgcn_global_load_lds(AS1(gA + (size_t)i * 8 * KAUG), AS3(sA + i * 8 * 64), 16, 0, 0);
      __builtin_amdgcn_global_load_lds(AS1(gB + (size_t)i * 8 * KAUG), AS3(sB + i * 8 * 64), 16, 0, 0);
    }
    __syncthreads();
#pragma unroll
    for (int ks = 0; ks < 2; ++ks) {
      int kch = ks * 4 + (lane >> 4);
      int ko = ((kch ^ (lane & 7)) << 3);             // swizzled read offset
      bf16x8 a[4], b[4];
#pragma unroll
      for (int f = 0; f < 4; ++f) a[f] = *(const bf16x8*)(As + (wm + f * 16 + (lane & 15)) * 64 + ko);
#pragma unroll
      for (int f = 0; f < 4; ++f) b[f] = *(const bf16x8*)(Bs + (wn + f * 16 + (lane & 15)) * 64 + ko);
#pragma unroll
      for (int fm = 0; fm < 4; ++fm)
#pragma unroll
        for (int fn = 0; fn < 4; ++fn)
          acc[fm][fn] = __builtin_amdgcn_mfma_f32_16x16x32_bf16(a[fm], b[fn], acc[fm][fn], 0, 0, 0);
    }
    __syncthreads();
    gA += 64; gB += 64;
  }
#pragma unroll
  for (int fm = 0; fm < 4; ++fm) {
    int row = bm + wm + fm * 16 + ((lane >> 4) << 2);
#pragma unroll
    for (int r = 0; r < 4; ++r) {
      float* orow = out + (size_t)(row + r) * OUTD + bn + wn + (lane & 15);
#pragma unroll
      for (int fn = 0; fn < 4; ++fn) orow[fn * 16] = acc[fm][fn][r];
    }
  }
}

extern "C" void kernel_launch(void* const* d_in, const int* in_sizes, int n_in,
                              void* d_out, int out_size, void* d_ws, size_t ws_size,
                              hipStream_t stream) {
  const float* x  = (const float*)d_in[0];
  const float* W  = (const float*)d_in[1];
  const float* gw = (const float*)d_in[2];
  const float* A  = (const float*)d_in[3];
  const float* B  = (const float*)d_in[4];
  float* out = (float*)d_out;

  char* ws = (char*)d_ws;
  unsigned short* Xa = (unsigned short*)(ws);                  // 8192*2176*2 = 35,651,584
  unsigned short* Wa = (unsigned short*)(ws + 35651584);       // 2048*2176*2 =  8,912,896
  // total 44,564,480 bytes (Ag / wte eliminated)

  k_fused<<<2432, 512, 0, stream>>>(x, gw, A, W, B, Xa, Wa);
  k_gemm <<<1024, 256, 0, stream>>>(Xa, Wa, out);
}

// Round 6
// 218.732 us; speedup vs baseline: 3.2755x; 2.4877x over previous
//
#include <hip/hip_runtime.h>
#include <hip/hip_bf16.h>
#include <stdint.h>

// Problem constants
#define T_TOK 8192   // B*S tokens
#define HID   2048
#define OUTD  2048
#define NE    8
#define RR    16
#define KAUG  2176   // 2048 + NE*RR
#define NH    128    // h columns (NE*RR)
#define NKT   34     // KAUG/64 K-tiles

typedef __bf16 bf16x8 __attribute__((ext_vector_type(8)));
typedef float  f32x4  __attribute__((ext_vector_type(4)));

#define AS1(p) ((__attribute__((address_space(1))) void*)(p))
#define AS3(p) ((__attribute__((address_space(3))) void*)(p))

__device__ inline unsigned short f2bf(float f) {
  unsigned int u = __builtin_bit_cast(unsigned int, f);
  unsigned int r = (u + 0x7fffu + ((u >> 16) & 1u)) >> 16;   // RNE
  return (unsigned short)r;
}

__device__ inline ushort4 f2bf4(float4 v) {
  ushort4 u;
  u.x = f2bf(v.x); u.y = f2bf(v.y); u.z = f2bf(v.z); u.w = f2bf(v.w);
  return u;
}

// ---- prep (VERBATIM round-1, proven 220.7 total): router + Xa core + all converts ----
__global__ __launch_bounds__(512) void k_prep(const float* __restrict__ x,
                                              const float* __restrict__ gw,
                                              const float* __restrict__ W,
                                              const float* __restrict__ Bw,
                                              const float* __restrict__ A,
                                              unsigned short* __restrict__ Xa,
                                              float* __restrict__ wte,
                                              unsigned short* __restrict__ Wa,
                                              unsigned short* __restrict__ Ag) {
  __shared__ float gws[NE * HID];     // 64 KiB
  if (blockIdx.x < 1024) {
#pragma unroll
    for (int i = 0; i < 8; ++i) {
      int idx = (i * 512 + (int)threadIdx.x) * 4;
      *(float4*)(gws + idx) = *(const float4*)(gw + idx);
    }
    __syncthreads();
    int w = threadIdx.x >> 6, lane = threadIdx.x & 63;
    int t = blockIdx.x * 8 + w;
    const float* xt = x + (size_t)t * HID;
    unsigned short* xo = Xa + (size_t)t * KAUG;
    double acc[8] = {0, 0, 0, 0, 0, 0, 0, 0};
#pragma unroll
    for (int i = 0; i < 8; ++i) {
      int k = (i * 64 + lane) * 4;
      float4 xv = *(const float4*)(xt + k);
      *(ushort4*)(xo + k) = f2bf4(xv);
#pragma unroll
      for (int e = 0; e < 8; ++e) {
        float4 gv = *(const float4*)(gws + e * HID + k);
        acc[e] += (double)xv.x * gv.x + (double)xv.y * gv.y +
                  (double)xv.z * gv.z + (double)xv.w * gv.w;
      }
    }
#pragma unroll
    for (int off = 32; off >= 1; off >>= 1)
#pragma unroll
      for (int e = 0; e < 8; ++e)
        acc[e] += __shfl_down(acc[e], off, 64);
    if (lane == 0) {
      int e0 = 0; double l0 = acc[0];
#pragma unroll
      for (int e = 1; e < 8; ++e) if (acc[e] > l0) { l0 = acc[e]; e0 = e; }
      int e1 = -1; double l1 = -1e300;
#pragma unroll
      for (int e = 0; e < 8; ++e) if (e != e0 && acc[e] > l1) { l1 = acc[e]; e1 = e; }
      double w0 = 16.0 / (1.0 + exp(l1 - l0));
      float o[8] = {0.f, 0.f, 0.f, 0.f, 0.f, 0.f, 0.f, 0.f};
      o[e0] = (float)w0;
      o[e1] = (float)(16.0 - w0);
      float4* p = (float4*)(wte + (size_t)t * 8);
      p[0] = make_float4(o[0], o[1], o[2], o[3]);
      p[1] = make_float4(o[4], o[5], o[6], o[7]);
    }
  } else {
    int b2 = blockIdx.x - 1024;
    if (b2 < 2048) {
      int tid = b2 * 512 + threadIdx.x;
      int row = tid >> 9, c = (tid & 511) << 2;
      float4 v = *(const float4*)(W + (size_t)row * HID + c);
      *(ushort4*)(Wa + (size_t)row * KAUG + c) = f2bf4(v);
    } else if (b2 < 2176) {
      int tid = (b2 - 2048) * 512 + threadIdx.x;
      int o = tid >> 5, j = (tid & 31) << 2;
      int e = j >> 4, r = j & 15;
      float4 v = *(const float4*)(Bw + (size_t)e * OUTD * RR + (size_t)o * RR + r);
      *(ushort4*)(Wa + (size_t)o * KAUG + 2048 + j) = f2bf4(v);
    } else {
      int tid = (b2 - 2176) * 512 + threadIdx.x;
      float4 v = *(const float4*)(A + (size_t)tid * 4);
      *(ushort4*)(Ag + (size_t)tid * 4) = f2bf4(v);
    }
  }
}

// ---- h-GEMM (VERBATIM round-1, proven): ring-of-4 counted-vmcnt ----
__global__ __launch_bounds__(256) void k_ha(const unsigned short* __restrict__ Xa,
                                            const unsigned short* __restrict__ Ag,
                                            const float* __restrict__ wte,
                                            unsigned short* __restrict__ XaW) {
  __shared__ unsigned short Xs[4][32 * 64];
  __shared__ unsigned short As[4][64 * 64];
  int tm = (blockIdx.x >> 1) * 32;
  int ch = (blockIdx.x & 1) * 64;
  int w = threadIdx.x >> 6, lane = threadIdx.x & 63;
  int lrow = lane >> 3;
  int lcol_s = (lane & 7) << 3;
  int lcol_g = ((lane & 7) ^ (lrow & 7)) << 3;

  const unsigned short* gX = Xa + (size_t)(tm + w * 8 + lrow) * KAUG + lcol_g;
  const unsigned short* gA = Ag + (size_t)(ch + w * 16 + lrow) * HID + lcol_g;
  int sxo = (w * 8 + lrow) * 64 + lcol_s;
  int sao = (w * 16 + lrow) * 64 + lcol_s;

  f32x4 acc[2] = {};

#define HA_STAGE(slot, koff) do {                                                         \
    __builtin_amdgcn_global_load_lds(AS1(gX + (koff)), AS3(&Xs[slot][0] + sxo), 16, 0, 0);\
    __builtin_amdgcn_global_load_lds(AS1(gA + (koff)), AS3(&As[slot][0] + sao), 16, 0, 0);\
    __builtin_amdgcn_global_load_lds(AS1(gA + (size_t)8 * HID + (koff)),                  \
                                     AS3(&As[slot][0] + 8 * 64 + sao), 16, 0, 0);         \
  } while (0)

#define HA_COMP(s) do {                                                                   \
    _Pragma("unroll")                                                                     \
    for (int ks = 0; ks < 2; ++ks) {                                                      \
      int kch = ks * 4 + (lane >> 4);                                                     \
      int ko = ((kch ^ (lane & 7)) << 3);                                                 \
      bf16x8 a = *(const bf16x8*)(&Xs[s][0] + ((w >> 1) * 16 + (lane & 15)) * 64 + ko);   \
      _Pragma("unroll")                                                                   \
      for (int fn = 0; fn < 2; ++fn) {                                                    \
        bf16x8 bv = *(const bf16x8*)(&As[s][0] + ((w & 1) * 32 + fn * 16 + (lane & 15)) * 64 + ko); \
        acc[fn] = __builtin_amdgcn_mfma_f32_16x16x32_bf16(a, bv, acc[fn], 0, 0, 0);       \
      }                                                                                   \
    }                                                                                     \
  } while (0)

  HA_STAGE(0, 0);
  HA_STAGE(1, 64);
  HA_STAGE(2, 128);
  for (int t = 0; t < 29; ++t) {
    asm volatile("s_waitcnt vmcnt(6)" ::: "memory");
    __builtin_amdgcn_s_barrier();
    HA_COMP(t & 3);
    __builtin_amdgcn_s_barrier();
    HA_STAGE((t + 3) & 3, (t + 3) * 64);
  }
  asm volatile("s_waitcnt vmcnt(6)" ::: "memory");
  __builtin_amdgcn_s_barrier();
  HA_COMP(1);
  asm volatile("s_waitcnt vmcnt(3)" ::: "memory");
  __builtin_amdgcn_s_barrier();
  HA_COMP(2);
  asm volatile("s_waitcnt vmcnt(0)" ::: "memory");
  __builtin_amdgcn_s_barrier();
  HA_COMP(3);
#undef HA_STAGE
#undef HA_COMP

  int q = lane >> 4;
#pragma unroll
  for (int fn = 0; fn < 2; ++fn) {
    int col = ch + (w & 1) * 32 + fn * 16 + (lane & 15);
    int e = col >> 4;
#pragma unroll
    for (int r = 0; r < 4; ++r) {
      int t = tm + (w >> 1) * 16 + q * 4 + r;
      float we = wte[(size_t)t * 8 + e];
      XaW[(size_t)t * KAUG + 2048 + col] = f2bf(we * acc[fn][r]);
    }
  }
}

// ---- main GEMM: 256x256 tile, 8 waves, ring-of-2 counted-vmcnt ----
// Same ring discipline as k_ha (proven R1/R3): a buffer is re-staged only after
// the barrier that ends all its reads; vmcnt(8) before compute counts exactly the
// 8 in-flight loads of stage(kt+1) -> stage(kt) guaranteed landed, never drains
// the prefetch queue. Fragment math / XOR swizzle / epilogue mapping verbatim
// from the proven 128^2 kernel (0 bank conflicts measured). Grid 256 = 1 blk/CU,
// 8 waves (2/SIMD); LDS 128 KiB. setprio(1) around the MFMA cluster (T5).
// NO min-waves clause (R4 lesson: it forced 64 VGPR -> scratch catastrophe).
__global__ __launch_bounds__(512) void k_gemm256(const unsigned short* __restrict__ Xa,
                                                 const unsigned short* __restrict__ Wa,
                                                 float* __restrict__ out) {
  __shared__ unsigned short Asl[2][256 * 64];   // 64 KiB
  __shared__ unsigned short Bsl[2][256 * 64];   // 64 KiB
  int bid = blockIdx.x;                  // 256 blocks
  int xcd = bid & 7, idx = bid >> 3;     // bijective: 32 blocks per XCD
  int bm = (xcd * 4 + (idx >> 3)) * 256; // 4 M-panels per XCD (L2-hot A)
  int bn = (idx & 7) * 256;              // N fastest within XCD
  int w = threadIdx.x >> 6, lane = threadIdx.x & 63;
  int wm = (w >> 2) * 128;               // wave M offset (2 waves)
  int wn = (w & 3) * 64;                 // wave N offset (4 waves)
  int lrow = lane >> 3;
  int lcol_s = (lane & 7) << 3;                       // LDS dest group (linear)
  int lcol_g = ((lane & 7) ^ (lrow & 7)) << 3;        // pre-swizzled global col

  const unsigned short* gA = Xa + (size_t)(bm + w * 8 + lrow) * KAUG + lcol_g;
  const unsigned short* gB = Wa + (size_t)(bn + w * 8 + lrow) * KAUG + lcol_g;
  int sO = (w * 8 + lrow) * 64 + lcol_s;              // dest (shorts); +i*64*64 per row-block

  // stage one full K-tile (A 256x64 + B 256x64) into buf p: 8 gll/thread
#define G_STAGE(p, kt) do {                                                        \
    _Pragma("unroll")                                                              \
    for (int i = 0; i < 4; ++i) {                                                  \
      __builtin_amdgcn_global_load_lds(AS1(gA + (size_t)i * 64 * KAUG + (kt) * 64),\
                                       AS3(&Asl[p][0] + sO + i * 64 * 64), 16, 0, 0); \
      __builtin_amdgcn_global_load_lds(AS1(gB + (size_t)i * 64 * KAUG + (kt) * 64),\
                                       AS3(&Bsl[p][0] + sO + i * 64 * 64), 16, 0, 0); \
    }                                                                              \
  } while (0)

  f32x4 acc[8][4] = {};

#define G_COMP(p) do {                                                             \
    __builtin_amdgcn_s_setprio(1);                                                 \
    _Pragma("unroll")                                                              \
    for (int kk = 0; kk < 2; ++kk) {                                               \
      int kch = kk * 4 + (lane >> 4);                                              \
      int ko = ((kch ^ (lane & 7)) << 3);                                          \
      bf16x8 b[4];                                                                 \
      _Pragma("unroll")                                                            \
      for (int n = 0; n < 4; ++n)                                                  \
        b[n] = *(const bf16x8*)(&Bsl[p][0] + (wn + n * 16 + (lane & 15)) * 64 + ko); \
      _Pragma("unroll")                                                            \
      for (int f = 0; f < 8; ++f) {                                                \
        bf16x8 a = *(const bf16x8*)(&Asl[p][0] + (wm + f * 16 + (lane & 15)) * 64 + ko); \
        _Pragma("unroll")                                                          \
        for (int n = 0; n < 4; ++n)                                                \
          acc[f][n] = __builtin_amdgcn_mfma_f32_16x16x32_bf16(a, b[n], acc[f][n], 0, 0, 0); \
      }                                                                            \
    }                                                                              \
    __builtin_amdgcn_s_setprio(0);                                                 \
  } while (0)

  // prologue: K-tiles 0,1 in flight (16 gll/thread)
  G_STAGE(0, 0);
  G_STAGE(1, 1);
  // main: kt = 0..32; peel kt=33. Parity-unrolled so buf index is compile-time.
  for (int kt = 0; kt < 32; kt += 2) {
    asm volatile("s_waitcnt vmcnt(8)" ::: "memory");   // stage(kt) landed; stage(kt+1) stays in flight
    __builtin_amdgcn_s_barrier();
    G_COMP(0);
    __builtin_amdgcn_s_barrier();                      // all reads of buf0 done
    if (kt + 2 < NKT) G_STAGE(0, kt + 2);
    asm volatile("s_waitcnt vmcnt(8)" ::: "memory");
    __builtin_amdgcn_s_barrier();
    G_COMP(1);
    __builtin_amdgcn_s_barrier();
    if (kt + 3 < NKT) G_STAGE(1, kt + 3);
  }
  // kt = 32 (buf0): stage(33) is the only newer in-flight group
  asm volatile("s_waitcnt vmcnt(8)" ::: "memory");
  __builtin_amdgcn_s_barrier();
  G_COMP(0);
  __builtin_amdgcn_s_barrier();
  // kt = 33 (buf1): epilogue drain
  asm volatile("s_waitcnt vmcnt(0)" ::: "memory");
  __builtin_amdgcn_s_barrier();
  G_COMP(1);
#undef G_STAGE
#undef G_COMP

  // epilogue: same C/D mapping as proven 128^2 kernel
#pragma unroll
  for (int f = 0; f < 8; ++f) {
    int row = bm + wm + f * 16 + ((lane >> 4) << 2);
#pragma unroll
    for (int r = 0; r < 4; ++r) {
      float* orow = out + (size_t)(row + r) * OUTD + bn + wn + (lane & 15);
#pragma unroll
      for (int n = 0; n < 4; ++n) orow[n * 16] = acc[f][n][r];
    }
  }
}

extern "C" void kernel_launch(void* const* d_in, const int* in_sizes, int n_in,
                              void* d_out, int out_size, void* d_ws, size_t ws_size,
                              hipStream_t stream) {
  const float* x  = (const float*)d_in[0];
  const float* W  = (const float*)d_in[1];
  const float* gw = (const float*)d_in[2];
  const float* A  = (const float*)d_in[3];
  const float* B  = (const float*)d_in[4];
  float* out = (float*)d_out;

  char* ws = (char*)d_ws;
  unsigned short* Xa  = (unsigned short*)(ws);                  // 8192*2176*2 = 35,651,584
  unsigned short* Wa  = (unsigned short*)(ws + 35651584);       // 2048*2176*2 =  8,912,896
  unsigned short* Ag  = (unsigned short*)(ws + 44564480);       //  128*2048*2 =    524,288
  float*          wte = (float*)        (ws + 45088768);        // 8192*8*4    =    262,144
  // total 45,350,912 bytes

  k_prep   <<<3328, 512, 0, stream>>>(x, gw, W, B, A, Xa, wte, Wa, Ag);
  k_ha     <<<512, 256, 0, stream>>>(Xa, Ag, wte, Xa);
  k_gemm256<<<256, 512, 0, stream>>>(Xa, Wa, out);
}